// Round 5
// baseline (207.029 us; speedup 1.0000x reference)
//
#include <hip/hip_runtime.h>
#include <hip/hip_bf16.h>
#include <stdint.h>

#define NB 2
#define NS 2048
#define ND 1024
#define NH 16
#define NDH 64
#define NT (NB*NS)   // 4096 tokens

using f32x4  = __attribute__((ext_vector_type(4))) float;
using f32x16 = __attribute__((ext_vector_type(16))) float;
using bf16x8 = __attribute__((ext_vector_type(8))) short;
using u32x4  = __attribute__((ext_vector_type(4))) unsigned int;
using uint2v = __attribute__((ext_vector_type(2))) unsigned int;

typedef __attribute__((address_space(1))) unsigned int as1_uint;
typedef __attribute__((address_space(3))) unsigned int as3_uint;

__device__ __forceinline__ void llds16(void* l, const void* g) {
    // async global->LDS, 16B per lane; LDS dest = wave-uniform base + lane*16
    __builtin_amdgcn_global_load_lds((as1_uint*)g, (as3_uint*)l, 16, 0, 0);
}

__device__ __forceinline__ f32x4 mfma16(bf16x8 a, bf16x8 b, f32x4 c) {
    return __builtin_amdgcn_mfma_f32_16x16x32_bf16(a, b, c, 0, 0, 0);
}
__device__ __forceinline__ f32x16 mfma32(bf16x8 a, bf16x8 b, f32x16 c) {
    return __builtin_amdgcn_mfma_f32_32x32x16_bf16(a, b, c, 0, 0, 0);
}

__device__ __forceinline__ unsigned short f2bf(float f) {
    union { __hip_bfloat16 h; unsigned short u; } cv;
    cv.h = __float2bfloat16(f);
    return cv.u;
}

// lane<32 / lane>=32 half reduces on the VALU pipe (no LDS latency)
__device__ __forceinline__ float fmax_x32(float v) {
    uint2v r = __builtin_amdgcn_permlane32_swap(__float_as_uint(v), __float_as_uint(v), false, false);
    return fmaxf(__uint_as_float(r.x), __uint_as_float(r.y));
}
__device__ __forceinline__ float fadd_x32(float v) {
    uint2v r = __builtin_amdgcn_permlane32_swap(__float_as_uint(v), __float_as_uint(v), false, false);
    return __uint_as_float(r.x) + __uint_as_float(r.y);
}

// ---------------- weight prep ----------------
// Wq/Wk/Wv: (H, D, DH) f32  ->  WcatT bf16 rows n = mat*1024 + h*64 + e, cols k=d
// Wq is pre-scaled by 0.125*log2(e) so attention scores are in log2 domain.
__global__ void k_wqkv(const float* __restrict__ Wq, const float* __restrict__ Wk,
                       const float* __restrict__ Wv, unsigned short* __restrict__ WT) {
    const float SCALEQ = 0.125f * 1.44269504088896f;
    int bid = blockIdx.x;
    int kt = bid & 15; bid >>= 4;      // D/64
    int h  = bid & 15; bid >>= 4;      // H
    int mat = bid;                     // 0,1,2
    const float* W = (mat == 0) ? Wq : (mat == 1) ? Wk : Wv;
    __shared__ float tile[64][65];
    int tid = threadIdx.x;
#pragma unroll
    for (int i = 0; i < 16; ++i) {
        int idx = tid + i * 256;
        int r = idx >> 6, e = idx & 63;                 // r: d-offset, e: head dim
        tile[r][e] = W[(size_t)h * ND * NDH + (size_t)(kt * 64 + r) * NDH + e];
    }
    __syncthreads();
#pragma unroll
    for (int i = 0; i < 16; ++i) {
        int idx = tid + i * 256;
        int e = idx >> 6, r = idx & 63;
        float v = tile[r][e];
        if (mat == 0) v *= SCALEQ;
        WT[(size_t)(mat * 1024 + h * 64 + e) * ND + kt * 64 + r] = f2bf(v);
    }
}

// W (D,D) f32 row-major -> WT bf16 (D,D) with WT[n][k] = W[k][n]
__global__ void k_wt(const float* __restrict__ W, unsigned short* __restrict__ WT) {
    int bid = blockIdx.x;
    int ntile = bid & 15;
    int ktile = bid >> 4;
    __shared__ float tile[64][65];
    int tid = threadIdx.x;
#pragma unroll
    for (int i = 0; i < 16; ++i) {
        int idx = tid + i * 256;
        int r = idx >> 6, c = idx & 63;
        tile[r][c] = W[(size_t)(ktile * 64 + r) * ND + ntile * 64 + c];
    }
    __syncthreads();
#pragma unroll
    for (int i = 0; i < 16; ++i) {
        int idx = tid + i * 256;
        int c = idx >> 6, r = idx & 63;
        WT[(size_t)(ntile * 64 + c) * ND + ktile * 64 + r] = f2bf(tile[r][c]);
    }
}

// ---------------- layernorm (f32 in -> bf16 out) ----------------
__global__ void k_ln(const float* __restrict__ x, const float* __restrict__ sc,
                     const float* __restrict__ bi, unsigned short* __restrict__ out) {
    int row = blockIdx.x;
    int tid = threadIdx.x;
    const float* xr = x + (size_t)row * ND;
    float4 v = reinterpret_cast<const float4*>(xr)[tid];
    float sum = v.x + v.y + v.z + v.w;
    float sq  = v.x * v.x + v.y * v.y + v.z * v.z + v.w * v.w;
#pragma unroll
    for (int off = 1; off < 64; off <<= 1) {
        sum += __shfl_xor(sum, off);
        sq  += __shfl_xor(sq, off);
    }
    __shared__ float ssum[4], ssq[4];
    int wave = tid >> 6;
    if ((tid & 63) == 0) { ssum[wave] = sum; ssq[wave] = sq; }
    __syncthreads();
    sum = ssum[0] + ssum[1] + ssum[2] + ssum[3];
    sq  = ssq[0] + ssq[1] + ssq[2] + ssq[3];
    float mu  = sum * (1.0f / ND);
    float var = sq * (1.0f / ND) - mu * mu;
    float rstd = rsqrtf(var + 1e-5f);
    float4 s4 = reinterpret_cast<const float4*>(sc)[tid];
    float4 b4 = reinterpret_cast<const float4*>(bi)[tid];
    ushort4 o;
    o.x = f2bf((v.x - mu) * rstd * s4.x + b4.x);
    o.y = f2bf((v.y - mu) * rstd * s4.y + b4.y);
    o.z = f2bf((v.z - mu) * rstd * s4.z + b4.z);
    o.w = f2bf((v.w - mu) * rstd * s4.w + b4.w);
    reinterpret_cast<ushort4*>(out + (size_t)row * ND)[tid] = o;
}

// ---------------- GEMM: C(MxN) = A(MxK,bf16) * Bt(NxK,bf16)^T ----------------
// 128x128 tile, BK=64, 4 waves 2x2, XOR-swizzled LDS, global_load_lds staging.
// 2-phase double-buffer: prefetch kt+1 with counted vmcnt(8), raw s_barrier
// (NOT __syncthreads, which drains vmcnt(0) and kills the pipeline).
template<bool BIAS, bool RELU, bool RES>
__global__ __launch_bounds__(256)
void k_gemm(const unsigned short* __restrict__ A, const unsigned short* __restrict__ Bt,
            const float* __restrict__ bias, const float* __restrict__ res,
            void* __restrict__ Cv, int N, int K) {
    __shared__ __align__(16) unsigned short As[2][128 * 64];
    __shared__ __align__(16) unsigned short Bs[2][128 * 64];
    int tid = threadIdx.x;
    int lane = tid & 63, wave = tid >> 6;
    int wm = wave >> 1, wn = wave & 1;
    int l16 = lane & 15, lg = lane >> 4;
    int ntiles = N >> 7;
    int wg = (blockIdx.x & 7) * (gridDim.x >> 3) + (blockIdx.x >> 3);  // XCD swizzle
    int mt = wg / ntiles;
    int nt = wg % ntiles;

    const unsigned short* Abase = A  + (size_t)(mt * 128) * K;
    const unsigned short* Bbase = Bt + (size_t)(nt * 128) * K;

    f32x4 acc[4][4];
#pragma unroll
    for (int i = 0; i < 4; ++i)
#pragma unroll
        for (int j = 0; j < 4; ++j) acc[i][j] = (f32x4){0.f, 0.f, 0.f, 0.f};

    int srow = tid >> 3;
    int sch  = tid & 7;
    int KT = K >> 6;

    auto STAGE = [&](int kt, int bufi) {
#pragma unroll
        for (int i = 0; i < 4; ++i) {
            int row = srow + i * 32;
            int cs = sch ^ (row & 7);
            llds16((char*)As[bufi] + wave * 1024 + i * 4096,
                   Abase + (size_t)row * K + kt * 64 + cs * 8);
        }
#pragma unroll
        for (int i = 0; i < 4; ++i) {
            int row = srow + i * 32;
            int cs = sch ^ (row & 7);
            llds16((char*)Bs[bufi] + wave * 1024 + i * 4096,
                   Bbase + (size_t)row * K + kt * 64 + cs * 8);
        }
    };

    STAGE(0, 0);
    for (int kt = 0; kt < KT; ++kt) {
        int cb = kt & 1;
        if (kt + 1 < KT) {
            STAGE(kt + 1, cb ^ 1);
            asm volatile("s_waitcnt vmcnt(8)" ::: "memory");
        } else {
            asm volatile("s_waitcnt vmcnt(0)" ::: "memory");
        }
        __builtin_amdgcn_s_barrier();

        bf16x8 af[4][2], bfb[4][2];
#pragma unroll
        for (int mi = 0; mi < 4; ++mi)
#pragma unroll
            for (int kc = 0; kc < 2; ++kc) {
                int row = wm * 64 + mi * 16 + l16;
                int ch = (kc * 4 + lg) ^ (row & 7);
                af[mi][kc] = *reinterpret_cast<const bf16x8*>((const char*)As[cb] + row * 128 + ch * 16);
            }
#pragma unroll
        for (int ni = 0; ni < 4; ++ni)
#pragma unroll
            for (int kc = 0; kc < 2; ++kc) {
                int row = wn * 64 + ni * 16 + l16;
                int ch = (kc * 4 + lg) ^ (row & 7);
                bfb[ni][kc] = *reinterpret_cast<const bf16x8*>((const char*)Bs[cb] + row * 128 + ch * 16);
            }
#pragma unroll
        for (int mi = 0; mi < 4; ++mi)
#pragma unroll
            for (int ni = 0; ni < 4; ++ni) {
                acc[mi][ni] = mfma16(af[mi][0], bfb[ni][0], acc[mi][ni]);
                acc[mi][ni] = mfma16(af[mi][1], bfb[ni][1], acc[mi][ni]);
            }
        __builtin_amdgcn_s_barrier();
    }

#pragma unroll
    for (int mi = 0; mi < 4; ++mi)
#pragma unroll
        for (int ni = 0; ni < 4; ++ni) {
            int col = nt * 128 + wn * 64 + ni * 16 + l16;
            float bv = BIAS ? bias[col] : 0.f;
#pragma unroll
            for (int r = 0; r < 4; ++r) {
                int row = mt * 128 + wm * 64 + mi * 16 + lg * 4 + r;
                float v = acc[mi][ni][r] + bv;
                if (RELU) v = fmaxf(v, 0.f);
                size_t idx = (size_t)row * N + col;
                if (RES) ((float*)Cv)[idx] = v + res[idx];
                else ((unsigned short*)Cv)[idx] = f2bf(v);
            }
        }
}

// ---------------- fused causal flash attention + residual ----------------
// 32x32 MFMA, in-register softmax (zero P-LDS, zero shuffles on the rescale).
// qk: (T x 2048) bf16 [Q|K per head]; VT: (1024 x 4096) bf16 = V^T per head.
// Per block: 128 q-rows (4 waves x 32), KVBLK=64, 3-buffer depth-2 prefetch.
// Grid 512: CU pair (qt=15-a, qt=a) sums to 34 kv-tiles -> uniform load; low 5
// bits = (b,h) so each head's K/V^T pins to one XCD L2.
// Swapped QK^T (C col = q = lane&31): per-lane m/l/alpha are q-local.
__global__ __launch_bounds__(256)
void k_attn(const unsigned short* __restrict__ qk, const unsigned short* __restrict__ VT,
            const float* __restrict__ x, float* __restrict__ x2) {
    constexpr int ldq = 2 * ND;
    int bid = blockIdx.x;
    int bh = bid & 31;
    int aq = (bid >> 5) & 7;
    int qt = (bid >> 8) ? aq : 15 - aq;     // heavy-first + pairing balance
    int h = bh & 15, b = bh >> 4;
    int tid = threadIdx.x;
    int lane = tid & 63, wave = tid >> 6;
    int l31 = lane & 31, hb = lane >> 5;

    const unsigned short* Qp = qk + (size_t)b * NS * ldq + h * NDH;
    const unsigned short* Kp = Qp + ND;
    const unsigned short* Vp = VT + (size_t)(h * NDH) * NT + b * NS;  // [feat][token]

    __shared__ __align__(16) unsigned short Ks[3][64 * 64];   // [buf][key][feat] swizzled
    __shared__ __align__(16) unsigned short Vs[3][64 * 64];   // [buf][feat][key] swizzled

    int srow = tid >> 3;         // 0..31
    int sch  = tid & 7;
    int nt = 2 * qt + 2;
    int qw = qt * 128 + wave * 32;    // wave's first q row
    int q  = qw + l31;                // this lane's q row

    // Q fragments (B-operand of K@Q^T): qf[s] = Q[q][16s + 8hb + j], log2-scaled
    bf16x8 qf[4];
#pragma unroll
    for (int s = 0; s < 4; ++s)
        qf[s] = *reinterpret_cast<const bf16x8*>(Qp + (size_t)q * ldq + 16 * s + 8 * hb);

    f32x16 ot0, ot1;
#pragma unroll
    for (int i = 0; i < 16; ++i) { ot0[i] = 0.f; ot1[i] = 0.f; }
    float m_run = -1.0e30f, l_part = 0.0f;

    auto STAGE = [&](int t, int bufi) {
#pragma unroll
        for (int i = 0; i < 2; ++i) {
            int row = srow + i * 32;
            int cs = sch ^ (row & 7);
            llds16((char*)Ks[bufi] + wave * 1024 + i * 4096,
                   Kp + (size_t)(t * 64 + row) * ldq + cs * 8);
        }
#pragma unroll
        for (int i = 0; i < 2; ++i) {
            int row = srow + i * 32;
            int cs = sch ^ (row & 7);
            llds16((char*)Vs[bufi] + wave * 1024 + i * 4096,
                   Vp + (size_t)row * NT + t * 64 + cs * 8);
        }
    };

    STAGE(0, 0);
    STAGE(1, 1);

    for (int t = 0; t < nt; ++t) {
        int buf = t % 3;
        if (t + 2 < nt) {
            STAGE(t + 2, (t + 2) % 3);
            asm volatile("s_waitcnt vmcnt(8)" ::: "memory");
        } else if (t + 1 < nt) {
            asm volatile("s_waitcnt vmcnt(4)" ::: "memory");
        } else {
            asm volatile("s_waitcnt vmcnt(0)" ::: "memory");
        }
        __builtin_amdgcn_s_barrier();

        bool active = (64 * t <= qw + 31);
        if (active) {
            const char* Kb = (const char*)Ks[buf];
            const char* Vb = (const char*)Vs[buf];

            // ---- ST = K @ Q^T (two 32-key tiles), log2 units ----
            f32x16 st0, st1;
#pragma unroll
            for (int i = 0; i < 16; ++i) { st0[i] = 0.f; st1[i] = 0.f; }
            __builtin_amdgcn_s_setprio(1);
#pragma unroll
            for (int s = 0; s < 4; ++s) {
                int ch = (2 * s + hb) ^ (l31 & 7);
                bf16x8 kf0 = *reinterpret_cast<const bf16x8*>(Kb + l31 * 128 + ch * 16);
                bf16x8 kf1 = *reinterpret_cast<const bf16x8*>(Kb + (32 + l31) * 128 + ch * 16);
                st0 = mfma32(kf0, qf[s], st0);
                st1 = mfma32(kf1, qf[s], st1);
            }
            __builtin_amdgcn_s_setprio(0);

            // ---- mask (diag tiles only) + per-lane max over 32 keys ----
            float sv0[16], sv1[16];
            float ma = -3.0e38f, mb2 = -3.0e38f, mc = -3.0e38f, md = -3.0e38f;
            bool domask = (64 * t + 63 > qw);
#pragma unroll
            for (int r = 0; r < 16; ++r) {
                int krow = (r & 3) + 8 * (r >> 2) + 4 * hb;
                float s0 = st0[r], s1 = st1[r];
                if (domask) {
                    int k0 = 64 * t + krow;
                    s0 = (k0 <= q) ? s0 : -1.0e30f;
                    s1 = (k0 + 32 <= q) ? s1 : -1.0e30f;
                }
                sv0[r] = s0; sv1[r] = s1;
                float m01 = fmaxf(s0, s1);
                if ((r & 3) == 0) ma = fmaxf(ma, m01);
                else if ((r & 3) == 1) mb2 = fmaxf(mb2, m01);
                else if ((r & 3) == 2) mc = fmaxf(mc, m01);
                else md = fmaxf(md, m01);
            }
            float mx = fmaxf(fmaxf(ma, mb2), fmaxf(mc, md));
            mx = fmax_x32(mx);     // both key-halves of this q column

            // defer-max (THR = 8 in log2 units)
            if (__ballot(mx > m_run + 8.0f)) {
                float mnew = fmaxf(m_run, mx);
                float alpha = exp2f(m_run - mnew);
                m_run = mnew;
                l_part *= alpha;
#pragma unroll
                for (int i = 0; i < 16; ++i) { ot0[i] *= alpha; ot1[i] *= alpha; }
            }

            // ---- P = exp2(S - m), pack to bf16, half-swap broadcast ----
            unsigned lo0[8], hi0[8], lo1[8], hi1[8];   // [m*2+pp]
            float ls = 0.f;
#pragma unroll
            for (int m = 0; m < 4; ++m) {
#pragma unroll
                for (int pp = 0; pp < 2; ++pp) {
                    int r = m * 4 + pp * 2;
                    float a0 = exp2f(sv0[r]     - m_run);
                    float b0 = exp2f(sv0[r + 1] - m_run);
                    float a1 = exp2f(sv1[r]     - m_run);
                    float b1 = exp2f(sv1[r + 1] - m_run);
                    ls += (a0 + b0) + (a1 + b1);
                    unsigned u0 = (unsigned)f2bf(a0) | ((unsigned)f2bf(b0) << 16);
                    unsigned u1 = (unsigned)f2bf(a1) | ((unsigned)f2bf(b1) << 16);
                    uint2v r0 = __builtin_amdgcn_permlane32_swap(u0, u0, false, false);
                    uint2v r1 = __builtin_amdgcn_permlane32_swap(u1, u1, false, false);
                    lo0[m * 2 + pp] = r0.x; hi0[m * 2 + pp] = r0.y;
                    lo1[m * 2 + pp] = r1.x; hi1[m * 2 + pp] = r1.y;
                }
            }
            l_part += ls;

            // ---- O^T += V^T @ P^T ----
            __builtin_amdgcn_s_setprio(1);
#pragma unroll
            for (int s = 0; s < 4; ++s) {
                int mb3 = 2 * (s & 1);
                unsigned u0, u1, u2, u3;
                if (s < 2) {
                    u0 = hb ? lo0[(mb3 + 1) * 2]     : lo0[mb3 * 2];
                    u1 = hb ? lo0[(mb3 + 1) * 2 + 1] : lo0[mb3 * 2 + 1];
                    u2 = hb ? hi0[(mb3 + 1) * 2]     : hi0[mb3 * 2];
                    u3 = hb ? hi0[(mb3 + 1) * 2 + 1] : hi0[mb3 * 2 + 1];
                } else {
                    u0 = hb ? lo1[(mb3 + 1) * 2]     : lo1[mb3 * 2];
                    u1 = hb ? lo1[(mb3 + 1) * 2 + 1] : lo1[mb3 * 2 + 1];
                    u2 = hb ? hi1[(mb3 + 1) * 2]     : hi1[mb3 * 2];
                    u3 = hb ? hi1[(mb3 + 1) * 2 + 1] : hi1[mb3 * 2 + 1];
                }
                u32x4 uu = {u0, u1, u2, u3};
                bf16x8 pf = __builtin_bit_cast(bf16x8, uu);
                int ch = (2 * s + hb) ^ (l31 & 7);
                bf16x8 vf0 = *reinterpret_cast<const bf16x8*>(Vb + l31 * 128 + ch * 16);
                bf16x8 vf1 = *reinterpret_cast<const bf16x8*>(Vb + (32 + l31) * 128 + ch * 16);
                ot0 = mfma32(vf0, pf, ot0);
                ot1 = mfma32(vf1, pf, ot1);
            }
            __builtin_amdgcn_s_setprio(0);
        }
        // protect buf[(t+1)%3..] before next iteration's prefetch overwrites
        __builtin_amdgcn_s_barrier();
    }

    // epilogue: l reduce across key-halves (lane-local q), x2 = x + O/l
    float l_run = fadd_x32(l_part);
    float linv = 1.0f / l_run;
    size_t rowb = (size_t)(b * NS + q) * ND + h * NDH;
#pragma unroll
    for (int g2 = 0; g2 < 4; ++g2) {
        int f0 = 8 * g2 + 4 * hb;
        float4 xr = *reinterpret_cast<const float4*>(x + rowb + f0);
        float4 o;
        o.x = xr.x + ot0[4 * g2 + 0] * linv;
        o.y = xr.y + ot0[4 * g2 + 1] * linv;
        o.z = xr.z + ot0[4 * g2 + 2] * linv;
        o.w = xr.w + ot0[4 * g2 + 3] * linv;
        *reinterpret_cast<float4*>(x2 + rowb + f0) = o;
        float4 xr1 = *reinterpret_cast<const float4*>(x + rowb + 32 + f0);
        float4 o1;
        o1.x = xr1.x + ot1[4 * g2 + 0] * linv;
        o1.y = xr1.y + ot1[4 * g2 + 1] * linv;
        o1.z = xr1.z + ot1[4 * g2 + 2] * linv;
        o1.w = xr1.w + ot1[4 * g2 + 3] * linv;
        *reinterpret_cast<float4*>(x2 + rowb + 32 + f0) = o1;
    }
}

// ---------------- launcher ----------------
extern "C" void kernel_launch(void* const* d_in, const int* in_sizes, int n_in,
                              void* d_out, int out_size, void* d_ws, size_t ws_size,
                              hipStream_t stream) {
    const float* x    = (const float*)d_in[0];
    // d_in[1] = padding_mask (all-true by construction; causal-only mask applied)
    const float* Wq   = (const float*)d_in[2];
    const float* Wk   = (const float*)d_in[3];
    const float* Wv   = (const float*)d_in[4];
    const float* ln1s = (const float*)d_in[5];
    const float* ln1b = (const float*)d_in[6];
    const float* ln2s = (const float*)d_in[7];
    const float* ln2b = (const float*)d_in[8];
    const float* W1   = (const float*)d_in[9];
    const float* b1   = (const float*)d_in[10];
    const float* W2   = (const float*)d_in[11];
    const float* b2   = (const float*)d_in[12];
    float* out = (float*)d_out;

    char* ws = (char*)d_ws;
    unsigned short* WcatT = (unsigned short*)(ws);              //  6,291,456 B
    unsigned short* W1T   = (unsigned short*)(ws + 6291456);    //  2,097,152 B
    unsigned short* W2T   = (unsigned short*)(ws + 8388608);    //  2,097,152 B
    unsigned short* hbuf  = (unsigned short*)(ws + 10485760);   //  8,388,608 B (h, then h2)
    unsigned short* qkbuf = (unsigned short*)(ws + 18874368);   // 16,777,216 B
    unsigned short* vtbuf = (unsigned short*)(ws + 35651584);   //  8,388,608 B (V^T)
    float*          x2    = (float*)(ws + 44040192);            // 16,777,216 B
    unsigned short* ubuf  = qkbuf;                               // overlay (dead after attn)

    k_wqkv<<<3 * 16 * 16, 256, 0, stream>>>(Wq, Wk, Wv, WcatT);
    k_wt<<<256, 256, 0, stream>>>(W1, W1T);
    k_wt<<<256, 256, 0, stream>>>(W2, W2T);
    k_ln<<<NT, 256, 0, stream>>>(x, ln1s, ln1b, hbuf);
    // Q|K projection: (4096 x 2048) = hbuf @ WcatT[0:2048]^T
    k_gemm<false, false, false><<<(NT / 128) * (2048 / 128), 256, 0, stream>>>(
        hbuf, WcatT, nullptr, nullptr, qkbuf, 2048, 1024);
    // V^T projection: (1024 x 4096) = WcatT[2048:3072] @ hbuf^T  (free transpose)
    k_gemm<false, false, false><<<(1024 / 128) * (NT / 128), 256, 0, stream>>>(
        WcatT + (size_t)2048 * 1024, hbuf, nullptr, nullptr, vtbuf, NT, 1024);
    k_attn<<<512, 256, 0, stream>>>(qkbuf, vtbuf, x, x2);
    k_ln<<<NT, 256, 0, stream>>>(x2, ln2s, ln2b, hbuf);
    k_gemm<true, true, false><<<(NT / 128) * (1024 / 128), 256, 0, stream>>>(
        hbuf, W1T, b1, nullptr, ubuf, 1024, 1024);
    k_gemm<true, false, true><<<(NT / 128) * (1024 / 128), 256, 0, stream>>>(
        ubuf, W2T, b2, x2, out, 1024, 1024);
}

// Round 6
// 156.002 us; speedup vs baseline: 1.3271x; 1.3271x over previous
//
#include <hip/hip_runtime.h>
#include <hip/hip_bf16.h>
#include <stdint.h>

#define NB 2
#define NS 2048
#define ND 1024
#define NH 16
#define NDH 64
#define NT (NB*NS)   // 4096 tokens

using f32x4  = __attribute__((ext_vector_type(4))) float;
using bf16x8 = __attribute__((ext_vector_type(8))) short;
using uint2v = __attribute__((ext_vector_type(2))) unsigned int;

typedef __attribute__((address_space(1))) unsigned int as1_uint;
typedef __attribute__((address_space(3))) unsigned int as3_uint;

__device__ __forceinline__ void llds16(void* l, const void* g) {
    // async global->LDS, 16B per lane; LDS dest = wave-uniform base + lane*16
    __builtin_amdgcn_global_load_lds((as1_uint*)g, (as3_uint*)l, 16, 0, 0);
}

__device__ __forceinline__ f32x4 mfma16(bf16x8 a, bf16x8 b, f32x4 c) {
    return __builtin_amdgcn_mfma_f32_16x16x32_bf16(a, b, c, 0, 0, 0);
}

__device__ __forceinline__ unsigned short f2bf(float f) {
    union { __hip_bfloat16 h; unsigned short u; } cv;
    cv.h = __float2bfloat16(f);
    return cv.u;
}

// cross-lane xor-16 / xor-32 reduces on the VALU pipe (no LDS latency)
__device__ __forceinline__ float fmax_x16(float v) {
    uint2v r = __builtin_amdgcn_permlane16_swap(__float_as_uint(v), __float_as_uint(v), false, false);
    return fmaxf(__uint_as_float(r.x), __uint_as_float(r.y));
}
__device__ __forceinline__ float fmax_x32(float v) {
    uint2v r = __builtin_amdgcn_permlane32_swap(__float_as_uint(v), __float_as_uint(v), false, false);
    return fmaxf(__uint_as_float(r.x), __uint_as_float(r.y));
}
__device__ __forceinline__ float fadd_x16(float v) {
    uint2v r = __builtin_amdgcn_permlane16_swap(__float_as_uint(v), __float_as_uint(v), false, false);
    return __uint_as_float(r.x) + __uint_as_float(r.y);
}
__device__ __forceinline__ float fadd_x32(float v) {
    uint2v r = __builtin_amdgcn_permlane32_swap(__float_as_uint(v), __float_as_uint(v), false, false);
    return __uint_as_float(r.x) + __uint_as_float(r.y);
}

// ---------------- weight prep ----------------
// Wq/Wk/Wv: (H, D, DH) f32  ->  WcatT bf16 rows n = mat*1024 + h*64 + e, cols k=d
// Wq is pre-scaled by 0.125*log2(e) so attention scores are in log2 domain.
__global__ void k_wqkv(const float* __restrict__ Wq, const float* __restrict__ Wk,
                       const float* __restrict__ Wv, unsigned short* __restrict__ WT) {
    const float SCALEQ = 0.125f * 1.44269504088896f;
    int bid = blockIdx.x;
    int kt = bid & 15; bid >>= 4;      // D/64
    int h  = bid & 15; bid >>= 4;      // H
    int mat = bid;                     // 0,1,2
    const float* W = (mat == 0) ? Wq : (mat == 1) ? Wk : Wv;
    __shared__ float tile[64][65];
    int tid = threadIdx.x;
#pragma unroll
    for (int i = 0; i < 16; ++i) {
        int idx = tid + i * 256;
        int r = idx >> 6, e = idx & 63;                 // r: d-offset, e: head dim
        tile[r][e] = W[(size_t)h * ND * NDH + (size_t)(kt * 64 + r) * NDH + e];
    }
    __syncthreads();
#pragma unroll
    for (int i = 0; i < 16; ++i) {
        int idx = tid + i * 256;
        int e = idx >> 6, r = idx & 63;
        float v = tile[r][e];
        if (mat == 0) v *= SCALEQ;
        WT[(size_t)(mat * 1024 + h * 64 + e) * ND + kt * 64 + r] = f2bf(v);
    }
}

// W (D,D) f32 row-major -> WT bf16 (D,D) with WT[n][k] = W[k][n]
__global__ void k_wt(const float* __restrict__ W, unsigned short* __restrict__ WT) {
    int bid = blockIdx.x;
    int ntile = bid & 15;
    int ktile = bid >> 4;
    __shared__ float tile[64][65];
    int tid = threadIdx.x;
#pragma unroll
    for (int i = 0; i < 16; ++i) {
        int idx = tid + i * 256;
        int r = idx >> 6, c = idx & 63;
        tile[r][c] = W[(size_t)(ktile * 64 + r) * ND + ntile * 64 + c];
    }
    __syncthreads();
#pragma unroll
    for (int i = 0; i < 16; ++i) {
        int idx = tid + i * 256;
        int c = idx >> 6, r = idx & 63;
        WT[(size_t)(ntile * 64 + c) * ND + ktile * 64 + r] = f2bf(tile[r][c]);
    }
}

// ---------------- layernorm (f32 in -> bf16 out) ----------------
__global__ void k_ln(const float* __restrict__ x, const float* __restrict__ sc,
                     const float* __restrict__ bi, unsigned short* __restrict__ out) {
    int row = blockIdx.x;
    int tid = threadIdx.x;
    const float* xr = x + (size_t)row * ND;
    float4 v = reinterpret_cast<const float4*>(xr)[tid];
    float sum = v.x + v.y + v.z + v.w;
    float sq  = v.x * v.x + v.y * v.y + v.z * v.z + v.w * v.w;
#pragma unroll
    for (int off = 1; off < 64; off <<= 1) {
        sum += __shfl_xor(sum, off);
        sq  += __shfl_xor(sq, off);
    }
    __shared__ float ssum[4], ssq[4];
    int wave = tid >> 6;
    if ((tid & 63) == 0) { ssum[wave] = sum; ssq[wave] = sq; }
    __syncthreads();
    sum = ssum[0] + ssum[1] + ssum[2] + ssum[3];
    sq  = ssq[0] + ssq[1] + ssq[2] + ssq[3];
    float mu  = sum * (1.0f / ND);
    float var = sq * (1.0f / ND) - mu * mu;
    float rstd = rsqrtf(var + 1e-5f);
    float4 s4 = reinterpret_cast<const float4*>(sc)[tid];
    float4 b4 = reinterpret_cast<const float4*>(bi)[tid];
    ushort4 o;
    o.x = f2bf((v.x - mu) * rstd * s4.x + b4.x);
    o.y = f2bf((v.y - mu) * rstd * s4.y + b4.y);
    o.z = f2bf((v.z - mu) * rstd * s4.z + b4.z);
    o.w = f2bf((v.w - mu) * rstd * s4.w + b4.w);
    reinterpret_cast<ushort4*>(out + (size_t)row * ND)[tid] = o;
}

// ---------------- GEMM: C(MxN) = A(MxK,bf16) * Bt(NxK,bf16)^T ----------------
// 128x128 tile, BK=64, 4 waves 2x2, XOR-swizzled LDS, global_load_lds staging.
// 2-phase double-buffer: prefetch kt+1 with counted vmcnt(8), raw s_barrier
// (NOT __syncthreads, which drains vmcnt(0) and kills the pipeline).
template<bool BIAS, bool RELU, bool RES>
__global__ __launch_bounds__(256)
void k_gemm(const unsigned short* __restrict__ A, const unsigned short* __restrict__ Bt,
            const float* __restrict__ bias, const float* __restrict__ res,
            void* __restrict__ Cv, int N, int K) {
    __shared__ __align__(16) unsigned short As[2][128 * 64];
    __shared__ __align__(16) unsigned short Bs[2][128 * 64];
    int tid = threadIdx.x;
    int lane = tid & 63, wave = tid >> 6;
    int wm = wave >> 1, wn = wave & 1;
    int l16 = lane & 15, lg = lane >> 4;
    int ntiles = N >> 7;
    int wg = (blockIdx.x & 7) * (gridDim.x >> 3) + (blockIdx.x >> 3);  // XCD swizzle
    int mt = wg / ntiles;
    int nt = wg % ntiles;

    const unsigned short* Abase = A  + (size_t)(mt * 128) * K;
    const unsigned short* Bbase = Bt + (size_t)(nt * 128) * K;

    f32x4 acc[4][4];
#pragma unroll
    for (int i = 0; i < 4; ++i)
#pragma unroll
        for (int j = 0; j < 4; ++j) acc[i][j] = (f32x4){0.f, 0.f, 0.f, 0.f};

    int srow = tid >> 3;
    int sch  = tid & 7;
    int KT = K >> 6;

    auto STAGE = [&](int kt, int bufi) {
#pragma unroll
        for (int i = 0; i < 4; ++i) {
            int row = srow + i * 32;
            int cs = sch ^ (row & 7);
            llds16((char*)As[bufi] + wave * 1024 + i * 4096,
                   Abase + (size_t)row * K + kt * 64 + cs * 8);
        }
#pragma unroll
        for (int i = 0; i < 4; ++i) {
            int row = srow + i * 32;
            int cs = sch ^ (row & 7);
            llds16((char*)Bs[bufi] + wave * 1024 + i * 4096,
                   Bbase + (size_t)row * K + kt * 64 + cs * 8);
        }
    };

    STAGE(0, 0);
    for (int kt = 0; kt < KT; ++kt) {
        int cb = kt & 1;
        if (kt + 1 < KT) {
            STAGE(kt + 1, cb ^ 1);
            asm volatile("s_waitcnt vmcnt(8)" ::: "memory");
        } else {
            asm volatile("s_waitcnt vmcnt(0)" ::: "memory");
        }
        __builtin_amdgcn_s_barrier();

        bf16x8 af[4][2], bfb[4][2];
#pragma unroll
        for (int mi = 0; mi < 4; ++mi)
#pragma unroll
            for (int kc = 0; kc < 2; ++kc) {
                int row = wm * 64 + mi * 16 + l16;
                int ch = (kc * 4 + lg) ^ (row & 7);
                af[mi][kc] = *reinterpret_cast<const bf16x8*>((const char*)As[cb] + row * 128 + ch * 16);
            }
#pragma unroll
        for (int ni = 0; ni < 4; ++ni)
#pragma unroll
            for (int kc = 0; kc < 2; ++kc) {
                int row = wn * 64 + ni * 16 + l16;
                int ch = (kc * 4 + lg) ^ (row & 7);
                bfb[ni][kc] = *reinterpret_cast<const bf16x8*>((const char*)Bs[cb] + row * 128 + ch * 16);
            }
#pragma unroll
        for (int mi = 0; mi < 4; ++mi)
#pragma unroll
            for (int ni = 0; ni < 4; ++ni) {
                acc[mi][ni] = mfma16(af[mi][0], bfb[ni][0], acc[mi][ni]);
                acc[mi][ni] = mfma16(af[mi][1], bfb[ni][1], acc[mi][ni]);
            }
        __builtin_amdgcn_s_barrier();
    }

#pragma unroll
    for (int mi = 0; mi < 4; ++mi)
#pragma unroll
        for (int ni = 0; ni < 4; ++ni) {
            int col = nt * 128 + wn * 64 + ni * 16 + l16;
            float bv = BIAS ? bias[col] : 0.f;
#pragma unroll
            for (int r = 0; r < 4; ++r) {
                int row = mt * 128 + wm * 64 + mi * 16 + lg * 4 + r;
                float v = acc[mi][ni][r] + bv;
                if (RELU) v = fmaxf(v, 0.f);
                size_t idx = (size_t)row * N + col;
                if (RES) ((float*)Cv)[idx] = v + res[idx];
                else ((unsigned short*)Cv)[idx] = f2bf(v);
            }
        }
}

// ---------------- fused causal flash attention + residual ----------------
// qk: (T x 2048) bf16 [Q|K per head]; VT: (1024 x 4096) bf16 = V^T per head.
// One q-tile (64 rows) per block, grid 1024 (all co-resident at 4 blocks/CU).
// qb mapping balances the RESIDENT set: CU slot c gets bids {c,c+256,c+512,
// c+768} (round-robin dispatch), whose qb = {31-s,16+s,15-s,s} sum to 62 for
// every s -> uniform 66 kv-tiles per CU, no tail. Each XCD sees only 4
// distinct (b,h) -> 2MB K/V^T pinned in its L2.
// K and V^T double-buffered in LDS via global_load_lds (counted vmcnt).
// Softmax: permlane max-reduce, per-lane l partial (reduced in epilogue).
// Scores in log2 domain (Wq pre-scaled by 0.125*log2e).
__global__ __launch_bounds__(256)
void k_attn(const unsigned short* __restrict__ qk, const unsigned short* __restrict__ VT,
            const float* __restrict__ x, float* __restrict__ x2) {
    constexpr int ldq = 2 * ND;
    int bid = blockIdx.x;
    int c  = bid & 255;
    int g  = bid >> 8;                 // 0..3 (resident-generation index)
    int s  = c >> 5;                   // 0..7
    int bh = c & 31;
    int qb = (g == 0) ? 31 - s : (g == 1) ? 16 + s : (g == 2) ? 15 - s : s;
    int h = bh & 15, b = bh >> 4;
    int tid = threadIdx.x;
    int lane = tid & 63, wave = tid >> 6;
    int l16 = lane & 15, lg = lane >> 4;

    const unsigned short* Qp = qk + (size_t)b * NS * ldq + h * NDH;
    const unsigned short* Kp = Qp + ND;
    const unsigned short* Vp = VT + (size_t)(h * NDH) * NT + b * NS;  // [feat][token], stride NT

    __shared__ __align__(16) unsigned short Ks[2][64 * 64];   // [buf][key][feat] swizzled
    __shared__ __align__(16) unsigned short Vs[2][64 * 64];   // [buf][feat][key] swizzled
    __shared__ __align__(16) unsigned short Ps[4][16 * 64];   // per-wave P [q][key] swizzled

    int srow = tid >> 3;         // 0..31
    int sch  = tid & 7;

    int nt = qb + 1;
    int qw = qb * 64 + wave * 16;     // wave's first q row (seq-local)

    // Q fragments (B-operand of K@Q^T), already scaled to log2 domain
    bf16x8 qf[2];
#pragma unroll
    for (int kc = 0; kc < 2; ++kc)
        qf[kc] = *reinterpret_cast<const bf16x8*>(Qp + (size_t)(qw + l16) * ldq + kc * 32 + lg * 8);

    f32x4 oacc[4];
#pragma unroll
    for (int i = 0; i < 4; ++i) oacc[i] = (f32x4){0.f, 0.f, 0.f, 0.f};
    float m_run = -1.0e30f, l_part = 0.0f;

    char* pbase = (char*)&Ps[wave][0] + l16 * 128;
    int psw = l16 & 7;                // row-swizzle key for this lane's P row

    // ---- prologue: stage K(0), V(0) ----
#pragma unroll
    for (int i = 0; i < 2; ++i) {
        int row = srow + i * 32;
        int cs = sch ^ (row & 7);
        llds16((char*)Ks[0] + wave * 1024 + i * 4096, Kp + (size_t)row * ldq + cs * 8);
    }
#pragma unroll
    for (int i = 0; i < 2; ++i) {
        int row = srow + i * 32;
        int cs = sch ^ (row & 7);
        llds16((char*)Vs[0] + wave * 1024 + i * 4096, Vp + (size_t)row * NT + cs * 8);
    }

    for (int t = 0; t < nt; ++t) {
        int cur = t & 1;
        const char* Kcur = (const char*)Ks[cur];
        const char* Vcur = (const char*)Vs[cur];

        // issue next K/V stage into the other buffer (4 llds16 stay in flight)
        if (t + 1 < nt) {
#pragma unroll
            for (int i = 0; i < 2; ++i) {
                int row = srow + i * 32;
                int cs = sch ^ (row & 7);
                llds16((char*)Ks[cur ^ 1] + wave * 1024 + i * 4096,
                       Kp + (size_t)((t + 1) * 64 + row) * ldq + cs * 8);
            }
#pragma unroll
            for (int i = 0; i < 2; ++i) {
                int row = srow + i * 32;
                int cs = sch ^ (row & 7);
                llds16((char*)Vs[cur ^ 1] + wave * 1024 + i * 4096,
                       Vp + (size_t)row * NT + (t + 1) * 64 + cs * 8);
            }
            asm volatile("s_waitcnt vmcnt(4)" ::: "memory");
        } else {
            asm volatile("s_waitcnt vmcnt(0)" ::: "memory");
        }
        __builtin_amdgcn_s_barrier();

        // ---- ST = K @ Q^T : lane holds ST[key = mtt*16+lg*4+r][q = l16] ----
        f32x4 st[4];
#pragma unroll
        for (int mtt = 0; mtt < 4; ++mtt) st[mtt] = (f32x4){0.f, 0.f, 0.f, 0.f};
        __builtin_amdgcn_s_setprio(1);
#pragma unroll
        for (int kc = 0; kc < 2; ++kc)
#pragma unroll
            for (int mtt = 0; mtt < 4; ++mtt) {
                int row = mtt * 16 + l16;
                int ch = (kc * 4 + lg) ^ (row & 7);
                bf16x8 kf = *reinterpret_cast<const bf16x8*>(Kcur + row * 128 + ch * 16);
                st[mtt] = mfma16(kf, qf[kc], st[mtt]);
            }
        __builtin_amdgcn_s_setprio(0);

        // online softmax per q-column (q = l16); mask only the diagonal tile
        float sv[4][4];
        float mx = -3.0e38f;
        if (t == qb) {
            int qg = qw + l16;
#pragma unroll
            for (int mtt = 0; mtt < 4; ++mtt)
#pragma unroll
                for (int r = 0; r < 4; ++r) {
                    int key = t * 64 + mtt * 16 + lg * 4 + r;
                    float s2 = (key <= qg) ? st[mtt][r] : -1.0e30f;
                    sv[mtt][r] = s2;
                    mx = fmaxf(mx, s2);
                }
        } else {
#pragma unroll
            for (int mtt = 0; mtt < 4; ++mtt)
#pragma unroll
                for (int r = 0; r < 4; ++r) {
                    float s2 = st[mtt][r];
                    sv[mtt][r] = s2;
                    mx = fmaxf(mx, s2);
                }
        }
        // cross-lane max over the 4 lanes of each q-column (VALU permlane, no LDS)
        mx = fmax_x16(mx);
        mx = fmax_x32(mx);

        // defer-max (THR = 8 in log2 units): rescale only when max grew a lot
        if (__ballot(mx > m_run + 8.0f)) {
            float mnew = fmaxf(m_run, mx);
            float alpha = exp2f(m_run - mnew);
            m_run = mnew;
            l_part *= alpha;
#pragma unroll
            for (int r = 0; r < 4; ++r) {
                float ar = __shfl(alpha, (lane & 48) | (lg * 4 + r));
#pragma unroll
                for (int ntt = 0; ntt < 4; ++ntt) oacc[ntt][r] *= ar;
            }
        }

#pragma unroll
        for (int mtt = 0; mtt < 4; ++mtt) {
            float p0 = exp2f(sv[mtt][0] - m_run);
            float p1 = exp2f(sv[mtt][1] - m_run);
            float p2 = exp2f(sv[mtt][2] - m_run);
            float p3 = exp2f(sv[mtt][3] - m_run);
            l_part += (p0 + p1) + (p2 + p3);
            // keys mtt*16+lg*4 .. +3 -> logical bytes b0..b0+7 (one b64 write)
            int b0 = mtt * 32 + lg * 8;
            int sb = ((((b0 >> 4) ^ psw) << 4) | (b0 & 15));
            uint2 u;
            u.x = (unsigned)f2bf(p0) | ((unsigned)f2bf(p1) << 16);
            u.y = (unsigned)f2bf(p2) | ((unsigned)f2bf(p3) << 16);
            *reinterpret_cast<uint2*>(pbase + sb) = u;
        }

        asm volatile("s_waitcnt lgkmcnt(0)" ::: "memory");

        // O += P @ V
        __builtin_amdgcn_s_setprio(1);
#pragma unroll
        for (int kc = 0; kc < 2; ++kc) {
            bf16x8 pa = *reinterpret_cast<const bf16x8*>(pbase + (((kc * 4 + lg) ^ psw) << 4));
#pragma unroll
            for (int ntt = 0; ntt < 4; ++ntt) {
                int vrow = ntt * 16 + l16;
                bf16x8 vb = *reinterpret_cast<const bf16x8*>(
                    Vcur + vrow * 128 + ((((kc * 4 + lg) ^ (vrow & 7)) << 4)));
                oacc[ntt] = mfma16(pa, vb, oacc[ntt]);
            }
        }
        __builtin_amdgcn_s_setprio(0);
        // protect Ks[cur]/Vs[cur] before next iteration's prefetch overwrites
        __builtin_amdgcn_s_barrier();
    }

    // epilogue: reduce l across the 4 lanes of each q-column, then x2 = x + O/l
    float l_run = fadd_x32(fadd_x16(l_part));
#pragma unroll
    for (int r = 0; r < 4; ++r) {
        float lv = __shfl(l_run, (lane & 48) | (lg * 4 + r));
        float linv = 1.0f / lv;
        int tkn = b * NS + qw + lg * 4 + r;
        size_t base = (size_t)tkn * ND + h * NDH;
#pragma unroll
        for (int ntt = 0; ntt < 4; ++ntt) {
            size_t idx = base + ntt * 16 + l16;
            x2[idx] = x[idx] + oacc[ntt][r] * linv;
        }
    }
}

// ---------------- launcher ----------------
extern "C" void kernel_launch(void* const* d_in, const int* in_sizes, int n_in,
                              void* d_out, int out_size, void* d_ws, size_t ws_size,
                              hipStream_t stream) {
    const float* x    = (const float*)d_in[0];
    // d_in[1] = padding_mask (all-true by construction; causal-only mask applied)
    const float* Wq   = (const float*)d_in[2];
    const float* Wk   = (const float*)d_in[3];
    const float* Wv   = (const float*)d_in[4];
    const float* ln1s = (const float*)d_in[5];
    const float* ln1b = (const float*)d_in[6];
    const float* ln2s = (const float*)d_in[7];
    const float* ln2b = (const float*)d_in[8];
    const float* W1   = (const float*)d_in[9];
    const float* b1   = (const float*)d_in[10];
    const float* W2   = (const float*)d_in[11];
    const float* b2   = (const float*)d_in[12];
    float* out = (float*)d_out;

    char* ws = (char*)d_ws;
    unsigned short* WcatT = (unsigned short*)(ws);              //  6,291,456 B
    unsigned short* W1T   = (unsigned short*)(ws + 6291456);    //  2,097,152 B
    unsigned short* W2T   = (unsigned short*)(ws + 8388608);    //  2,097,152 B
    unsigned short* hbuf  = (unsigned short*)(ws + 10485760);   //  8,388,608 B (h, then h2)
    unsigned short* qkbuf = (unsigned short*)(ws + 18874368);   // 16,777,216 B
    unsigned short* vtbuf = (unsigned short*)(ws + 35651584);   //  8,388,608 B (V^T)
    float*          x2    = (float*)(ws + 44040192);            // 16,777,216 B
    unsigned short* ubuf  = qkbuf;                               // overlay (dead after attn)

    k_wqkv<<<3 * 16 * 16, 256, 0, stream>>>(Wq, Wk, Wv, WcatT);
    k_wt<<<256, 256, 0, stream>>>(W1, W1T);
    k_wt<<<256, 256, 0, stream>>>(W2, W2T);
    k_ln<<<NT, 256, 0, stream>>>(x, ln1s, ln1b, hbuf);
    // Q|K projection: (4096 x 2048) = hbuf @ WcatT[0:2048]^T
    k_gemm<false, false, false><<<(NT / 128) * (2048 / 128), 256, 0, stream>>>(
        hbuf, WcatT, nullptr, nullptr, qkbuf, 2048, 1024);
    // V^T projection: (1024 x 4096) = WcatT[2048:3072] @ hbuf^T  (free transpose)
    k_gemm<false, false, false><<<(1024 / 128) * (NT / 128), 256, 0, stream>>>(
        WcatT + (size_t)2048 * 1024, hbuf, nullptr, nullptr, vtbuf, NT, 1024);
    k_attn<<<NB * NH * 32, 256, 0, stream>>>(qkbuf, vtbuf, x, x2);
    k_ln<<<NT, 256, 0, stream>>>(x2, ln2s, ln2b, hbuf);
    k_gemm<true, true, false><<<(NT / 128) * (1024 / 128), 256, 0, stream>>>(
        hbuf, W1T, b1, nullptr, ubuf, 1024, 1024);
    k_gemm<true, false, true><<<(NT / 128) * (1024 / 128), 256, 0, stream>>>(
        ubuf, W2T, b2, x2, out, 1024, 1024);
}